// Round 12
// baseline (491.609 us; speedup 1.0000x reference)
//
#include <hip/hip_runtime.h>

// ---------------- problem constants ----------------
constexpr int CB = 64;          // batch
constexpr int CHH = 14, CWW = 14;
constexpr int CN = 196;         // CHH*CWW
constexpr int CC = 1024;        // channels
constexpr int CROWS = CB * CN;  // 12544
constexpr int CKW = 8;          // rfft bins along W

// twiddles: cos/sin(2*pi*m/14), m=0..13
constexpr float C14[14] = {
  1.0f, 0.9009688679024191f, 0.6234898018587336f, 0.2225209339563144f,
  -0.2225209339563144f, -0.6234898018587336f, -0.9009688679024191f, -1.0f,
  -0.9009688679024191f, -0.6234898018587336f, -0.2225209339563144f,
  0.2225209339563144f, 0.6234898018587336f, 0.9009688679024191f };
constexpr float S14[14] = {
  0.0f, 0.4338837391175581f, 0.7818314824680298f, 0.9749279121818236f,
  0.9749279121818236f, 0.7818314824680298f, 0.4338837391175581f, 0.0f,
  -0.4338837391175581f, -0.7818314824680298f, -0.9749279121818236f,
  -0.9749279121818236f, -0.7818314824680298f, -0.4338837391175581f };

typedef __attribute__((ext_vector_type(8))) short bf16x8;
typedef __attribute__((ext_vector_type(4))) float f32x4;

__device__ __forceinline__ unsigned short f2bf(float f) {
  unsigned u = __builtin_bit_cast(unsigned, f);
  u += 0x7FFFu + ((u >> 16) & 1u);   // RNE
  return (unsigned short)(u >> 16);
}
__device__ __forceinline__ float bf2f(unsigned short h) {
  return __builtin_bit_cast(float, (unsigned)h << 16);
}
__device__ __forceinline__ unsigned pack2(float re, float im) {
  return (unsigned)f2bf(re) | ((unsigned)f2bf(im) << 16);
}

__device__ __forceinline__ void gload_lds16(const void* g, void* l) {
  __builtin_amdgcn_global_load_lds(
      (const __attribute__((address_space(1))) void*)g,
      (__attribute__((address_space(3))) void*)l, 16, 0, 0);
}

#define WAITV(N)  asm volatile("s_waitcnt vmcnt(" #N ")" ::: "memory")

// ---------------- fused LN1 + rfft along W ----------------
__global__ __launch_bounds__(256)
void ln_fftw(const float* __restrict__ x, const float* __restrict__ gam,
             const float* __restrict__ bet, unsigned* __restrict__ Az)
{
  const int t = threadIdx.x;
  const int bid = blockIdx.x;             // b*14 + h
  const int h = bid % 14;
  const int b = bid / 14;
  const int c4 = t * 4;
  const size_t base = ((size_t)b * CN + (size_t)h * CWW) * CC + c4;
  float v[14][4];
  float sw[14], qw[14];
  #pragma unroll
  for (int w = 0; w < 14; w++) {
    const float4 u = *(const float4*)(x + base + (size_t)w * CC);
    v[w][0] = u.x; v[w][1] = u.y; v[w][2] = u.z; v[w][3] = u.w;
    sw[w] = u.x + u.y + u.z + u.w;
    qw[w] = u.x*u.x + u.y*u.y + u.z*u.z + u.w*u.w;
  }
  __shared__ float redS[14][4], redQ[14][4];
  const int wid = t >> 6, lane = t & 63;
  #pragma unroll
  for (int w = 0; w < 14; w++) {
    float a = sw[w], q = qw[w];
    #pragma unroll
    for (int o = 32; o > 0; o >>= 1) { a += __shfl_down(a, o); q += __shfl_down(q, o); }
    if (lane == 0) { redS[w][wid] = a; redQ[w][wid] = q; }
  }
  __syncthreads();
  const float4 g4 = *(const float4*)(gam + c4);
  const float4 b4 = *(const float4*)(bet + c4);
  const float gg[4] = {g4.x, g4.y, g4.z, g4.w};
  const float bb[4] = {b4.x, b4.y, b4.z, b4.w};
  #pragma unroll
  for (int w = 0; w < 14; w++) {
    const float a = redS[w][0] + redS[w][1] + redS[w][2] + redS[w][3];
    const float q = redQ[w][0] + redQ[w][1] + redQ[w][2] + redQ[w][3];
    const float mean = a * (1.0f / CC);
    const float var  = q * (1.0f / CC) - mean * mean;
    const float r = rsqrtf(var + 1e-5f);
    #pragma unroll
    for (int j = 0; j < 4; j++)
      v[w][j] = (v[w][j] - mean) * r * gg[j] + bb[j];
  }
  const size_t obase = (((size_t)b * CHH + h) * CKW) * CC + c4;
  #pragma unroll
  for (int kw = 0; kw < 8; kw++) {
    float sr[4] = {}, si[4] = {};
    #pragma unroll
    for (int w = 0; w < 14; w++) {
      const int m = (w * kw) % 14;
      #pragma unroll
      for (int j = 0; j < 4; j++) {
        sr[j] += v[w][j] * C14[m];
        si[j] -= v[w][j] * S14[m];
      }
    }
    uint4 o;
    o.x = pack2(sr[0], si[0]); o.y = pack2(sr[1], si[1]);
    o.z = pack2(sr[2], si[2]); o.w = pack2(sr[3], si[3]);
    *(uint4*)(Az + obase + (size_t)kw * CC) = o;
  }
}

// ---------------- fft along H + filter + ifft along H (packed, 2 ch/thread) ----------------
__global__ __launch_bounds__(256)
void fft_h_filt(const unsigned* __restrict__ Az, const float* __restrict__ cw,
                unsigned* __restrict__ Bz)
{
  const int t = threadIdx.x;
  const int bid = blockIdx.x;             // ((b*8)+kw)*2 + half
  const int half = bid & 1;
  const int tmp = bid >> 1;
  const int kw = tmp & 7;
  const int b = tmp >> 3;
  const int c2 = half * 512 + t * 2;
  const size_t base = (((size_t)b * CHH) * CKW + kw) * CC + c2;  // h stride = CKW*CC
  float ar[14][2], ai[14][2];
  #pragma unroll
  for (int h = 0; h < 14; h++) {
    const uint2 u = *(const uint2*)(Az + base + (size_t)h * (CKW * CC));
    ar[h][0] = bf2f((unsigned short)(u.x & 0xffff)); ai[h][0] = bf2f((unsigned short)(u.x >> 16));
    ar[h][1] = bf2f((unsigned short)(u.y & 0xffff)); ai[h][1] = bf2f((unsigned short)(u.y >> 16));
  }
  float fr[14][2], fi[14][2];
  #pragma unroll
  for (int kh = 0; kh < 14; kh++) {
    float yr[2] = {}, yi[2] = {};
    #pragma unroll
    for (int h = 0; h < 14; h++) {
      const int m = (h * kh) % 14;
      #pragma unroll
      for (int j = 0; j < 2; j++) {
        yr[j] += ar[h][j] * C14[m] + ai[h][j] * S14[m];
        yi[j] += ai[h][j] * C14[m] - ar[h][j] * S14[m];
      }
    }
    const float4 w4 = *(const float4*)(cw + ((size_t)(kh * CKW + kw) * CC + c2) * 2);
    fr[kh][0] = yr[0] * w4.x - yi[0] * w4.y; fi[kh][0] = yr[0] * w4.y + yi[0] * w4.x;
    fr[kh][1] = yr[1] * w4.z - yi[1] * w4.w; fi[kh][1] = yr[1] * w4.w + yi[1] * w4.z;
  }
  #pragma unroll
  for (int h = 0; h < 14; h++) {
    float sr[2] = {}, si[2] = {};
    #pragma unroll
    for (int kh = 0; kh < 14; kh++) {
      const int m = (h * kh) % 14;
      #pragma unroll
      for (int j = 0; j < 2; j++) {
        sr[j] += fr[kh][j] * C14[m] - fi[kh][j] * S14[m];
        si[j] += fr[kh][j] * S14[m] + fi[kh][j] * C14[m];
      }
    }
    uint2 o;
    o.x = pack2(sr[0], si[0]); o.y = pack2(sr[1], si[1]);
    *(uint2*)(Bz + base + (size_t)h * (CKW * CC)) = o;
  }
}

// ---------------- fused irfft along W + LN2 -> bf16 A1 ----------------
__global__ __launch_bounds__(256)
void fftinv_ln(const unsigned* __restrict__ Bz, const float* __restrict__ gam,
               const float* __restrict__ bet, unsigned short* __restrict__ A1)
{
  const int t = threadIdx.x;
  const int bid = blockIdx.x;             // b*14 + h
  const int h = bid % 14;
  const int b = bid / 14;
  const int c4 = t * 4;
  const size_t ibase = (((size_t)b * CHH + h) * CKW) * CC + c4;
  float br[8][4], bi[8][4];
  #pragma unroll
  for (int k = 0; k < 8; k++) {
    const uint4 u = *(const uint4*)(Bz + ibase + (size_t)k * CC);
    br[k][0] = bf2f((unsigned short)(u.x & 0xffff)); bi[k][0] = bf2f((unsigned short)(u.x >> 16));
    br[k][1] = bf2f((unsigned short)(u.y & 0xffff)); bi[k][1] = bf2f((unsigned short)(u.y >> 16));
    br[k][2] = bf2f((unsigned short)(u.z & 0xffff)); bi[k][2] = bf2f((unsigned short)(u.z >> 16));
    br[k][3] = bf2f((unsigned short)(u.w & 0xffff)); bi[k][3] = bf2f((unsigned short)(u.w >> 16));
  }
  float y[14][4];
  float sw[14], qw[14];
  #pragma unroll
  for (int w = 0; w < 14; w++) {
    float s[4];
    #pragma unroll
    for (int j = 0; j < 4; j++)
      s[j] = br[0][j] + ((w & 1) ? -br[7][j] : br[7][j]);
    #pragma unroll
    for (int k = 1; k < 7; k++) {
      const int m = (w * k) % 14;
      #pragma unroll
      for (int j = 0; j < 4; j++)
        s[j] += 2.0f * (br[k][j] * C14[m] - bi[k][j] * S14[m]);
    }
    float a = 0.f, q = 0.f;
    #pragma unroll
    for (int j = 0; j < 4; j++) {
      y[w][j] = s[j] * (1.0f / 196.0f);
      a += y[w][j];
      q += y[w][j] * y[w][j];
    }
    sw[w] = a; qw[w] = q;
  }
  __shared__ float redS[14][4], redQ[14][4];
  const int wid = t >> 6, lane = t & 63;
  #pragma unroll
  for (int w = 0; w < 14; w++) {
    float a = sw[w], q = qw[w];
    #pragma unroll
    for (int o = 32; o > 0; o >>= 1) { a += __shfl_down(a, o); q += __shfl_down(q, o); }
    if (lane == 0) { redS[w][wid] = a; redQ[w][wid] = q; }
  }
  __syncthreads();
  const float4 g4 = *(const float4*)(gam + c4);
  const float4 b4 = *(const float4*)(bet + c4);
  const float gg[4] = {g4.x, g4.y, g4.z, g4.w};
  const float bb[4] = {b4.x, b4.y, b4.z, b4.w};
  #pragma unroll
  for (int w = 0; w < 14; w++) {
    const float a = redS[w][0] + redS[w][1] + redS[w][2] + redS[w][3];
    const float q = redQ[w][0] + redQ[w][1] + redQ[w][2] + redQ[w][3];
    const float mean = a * (1.0f / CC);
    const float var  = q * (1.0f / CC) - mean * mean;
    const float r = rsqrtf(var + 1e-5f);
    ushort4 o;
    o.x = f2bf((y[w][0] - mean) * r * gg[0] + bb[0]);
    o.y = f2bf((y[w][1] - mean) * r * gg[1] + bb[1]);
    o.z = f2bf((y[w][2] - mean) * r * gg[2] + bb[2]);
    o.w = f2bf((y[w][3] - mean) * r * gg[3] + bb[3]);
    *(ushort4*)(A1 + ((size_t)b * CN + (size_t)h * CWW + w) * CC + c4) = o;
  }
}

// ---------------- transpose fp32 [R,Cc] -> bf16 [Cc,R] ----------------
__global__ __launch_bounds__(256)
void transpose_f32_bf16(const float* __restrict__ in, unsigned short* __restrict__ out,
                        int R, int Ccols)
{
  __shared__ float tile[32][33];
  const int tx = threadIdx.x & 31;
  const int ty = threadIdx.x >> 5;     // 0..7
  const int cb = blockIdx.x * 32;
  const int rb = blockIdx.y * 32;
  #pragma unroll
  for (int i = 0; i < 32; i += 8)
    tile[ty + i][tx] = in[(size_t)(rb + ty + i) * Ccols + cb + tx];
  __syncthreads();
  #pragma unroll
  for (int i = 0; i < 32; i += 8)
    out[(size_t)(cb + ty + i) * R + rb + tx] = f2bf(tile[tx][ty + i]);
}

// ---------------- 128Mx256N bf16 GEMM, asymmetric 128x64 wave tiles ----------------
// LDS-reuse upgrade: per ks each wave reads bf[4] once, reuses across 8 af ->
// 24 LDS reads per 64 MFMA (0.0229 B/FLOP, -27% vs 128x128) -> MFMA-dominant.
// LDS: A[128][64] 16KB + B[256][64] 32KB single-buffered = 48KB; acc 8x4 = 128
// VGPR -> launch_bounds(256,2): 2 blocks/CU (grid 1568 = 6.1/CU, 3 rounds).
// Same verified swizzle as R10 (conflicts = 0): rows are 128B, read byte
// ^= (row&7)<<4, staged via inverse-swizzled global source (rule #21).
template<int DO_GELU>
__global__ __launch_bounds__(256, 2)
void gemm128x256(const unsigned short* __restrict__ A, const unsigned short* __restrict__ BT,
                 const float* __restrict__ bias, unsigned short* __restrict__ C,
                 int M, int N, int K)
{
  __shared__ __align__(16) char sA[16384];
  __shared__ __align__(16) char sB[32768];
  const int t = threadIdx.x;
  const int wn = t >> 6, lane = t & 63;        // 4 waves across N
  const int lrow = lane & 15, qk = lane >> 4;
  const int dq = qk << 4;

  // block mapping: groups of 8 brow-panels; within a group by-major then bx
  const int nbx = N >> 8, nby = M >> 7;
  const int per = nbx << 3;
  const int fullg = nby >> 3;
  int by, bx;
  if ((int)blockIdx.x < fullg * per) {
    const int g = blockIdx.x / per, r = blockIdx.x % per;
    by = (g << 3) + (r & 7); bx = r >> 3;
  } else {
    const int r = blockIdx.x - fullg * per;
    const int rem = nby - (fullg << 3);
    by = (fullg << 3) + r % rem; bx = r / rem;
  }
  const int brow = by << 7, bcol = bx << 8;

  // staging constants: A 4 regions of 32 rows, B 8 regions of 32 rows
  const int vr = t >> 3;                       // row within region (0..31)
  const int cl = ((t ^ (t >> 3)) & 7) << 3;    // inverse-swizzled elem col
  const int dstb = t * 16;                     // linear dest byte within region

  f32x4 acc[8][4] = {};

  for (int k0 = 0; k0 < K; k0 += 64) {
    __syncthreads();
    #pragma unroll
    for (int i = 0; i < 4; ++i)
      gload_lds16(A  + (size_t)(brow + i * 32 + vr) * K + k0 + cl, sA + i * 4096 + dstb);
    #pragma unroll
    for (int i = 0; i < 8; ++i)
      gload_lds16(BT + (size_t)(bcol + i * 32 + vr) * K + k0 + cl, sB + i * 4096 + dstb);
    WAITV(0);
    __syncthreads();
    #pragma unroll
    for (int ks = 0; ks < 2; ++ks) {
      bf16x8 bf[4];
      #pragma unroll
      for (int nf = 0; nf < 4; ++nf) {
        const int row = wn * 64 + nf * 16 + lrow;
        bf[nf] = *(const bf16x8*)(sB + row * 128 + (((ks << 6) | dq) ^ ((row & 7) << 4)));
      }
      #pragma unroll
      for (int mf = 0; mf < 8; ++mf) {
        const int row = mf * 16 + lrow;
        const bf16x8 af = *(const bf16x8*)(sA + row * 128 +
                           (((ks << 6) | dq) ^ ((row & 7) << 4)));
        #pragma unroll
        for (int nf = 0; nf < 4; ++nf)
          acc[mf][nf] = __builtin_amdgcn_mfma_f32_16x16x32_bf16(af, bf[nf],
                                                                acc[mf][nf], 0, 0, 0);
      }
    }
  }

  // epilogue: bias (+GELU) + bf16 store
  #pragma unroll
  for (int mf = 0; mf < 8; ++mf) {
    #pragma unroll
    for (int nf = 0; nf < 4; ++nf) {
      const int ccol = bcol + wn * 64 + nf * 16 + lrow;
      const float bb = bias[ccol];
      #pragma unroll
      for (int j = 0; j < 4; ++j) {
        const int r = brow + mf * 16 + qk * 4 + j;
        float v = acc[mf][nf][j] + bb;
        if (DO_GELU) v = 0.5f * v * (1.0f + erff(v * 0.70710678118654752f));
        C[(size_t)r * N + ccol] = f2bf(v);
      }
    }
  }
}

// ---------------- 128x128 bf16 GEMM, m97 structure, BK=64, 4 blocks/CU ----------------
// (unchanged from R10: 140us/dispatch, MfmaUtil 33%, 0 bank conflicts)
template<int DO_GELU>
__global__ __launch_bounds__(256, 4)
void gemm128(const unsigned short* __restrict__ A, const unsigned short* __restrict__ BT,
             const float* __restrict__ bias, unsigned short* __restrict__ C,
             int M, int N, int K)
{
  __shared__ __align__(16) char sA[16384];
  __shared__ __align__(16) char sB[16384];
  const int t = threadIdx.x;
  const int wid = t >> 6, lane = t & 63;
  const int wm = wid >> 1, wn = wid & 1;
  const int lrow = lane & 15, qk = lane >> 4;
  const int dq = qk << 4;

  const int nbx = N >> 7, nby = M >> 7;
  const int per = nbx << 3;
  const int fullg = nby >> 3;
  int by, bx;
  if ((int)blockIdx.x < fullg * per) {
    const int g = blockIdx.x / per, r = blockIdx.x % per;
    by = (g << 3) + (r & 7); bx = r >> 3;
  } else {
    const int r = blockIdx.x - fullg * per;
    const int rem = nby - (fullg << 3);
    by = (fullg << 3) + r % rem; bx = r / rem;
  }
  const int brow = by << 7, bcol = bx << 7;

  const int vr = t >> 3;
  const int cl = ((t ^ (t >> 3)) & 7) << 3;
  const int dstb = t * 16;

  f32x4 acc[4][4] = {};

  for (int k0 = 0; k0 < K; k0 += 64) {
    __syncthreads();
    #pragma unroll
    for (int i = 0; i < 4; ++i) {
      gload_lds16(A  + (size_t)(brow + i * 32 + vr) * K + k0 + cl, sA + i * 4096 + dstb);
      gload_lds16(BT + (size_t)(bcol + i * 32 + vr) * K + k0 + cl, sB + i * 4096 + dstb);
    }
    WAITV(0);
    __syncthreads();
    #pragma unroll
    for (int ks = 0; ks < 2; ++ks) {
      bf16x8 af[4], bf[4];
      #pragma unroll
      for (int mf = 0; mf < 4; ++mf) {
        const int row = wm * 64 + mf * 16 + lrow;
        af[mf] = *(const bf16x8*)(sA + row * 128 + (((ks << 6) | dq) ^ ((row & 7) << 4)));
      }
      #pragma unroll
      for (int nf = 0; nf < 4; ++nf) {
        const int row = wn * 64 + nf * 16 + lrow;
        bf[nf] = *(const bf16x8*)(sB + row * 128 + (((ks << 6) | dq) ^ ((row & 7) << 4)));
      }
      #pragma unroll
      for (int mf = 0; mf < 4; ++mf)
        #pragma unroll
        for (int nf = 0; nf < 4; ++nf)
          acc[mf][nf] = __builtin_amdgcn_mfma_f32_16x16x32_bf16(af[mf], bf[nf],
                                                                acc[mf][nf], 0, 0, 0);
    }
  }

  #pragma unroll
  for (int mf = 0; mf < 4; ++mf) {
    #pragma unroll
    for (int nf = 0; nf < 4; ++nf) {
      const int ccol = bcol + wn * 64 + nf * 16 + lrow;
      const float bb = bias[ccol];
      #pragma unroll
      for (int j = 0; j < 4; ++j) {
        const int r = brow + wm * 64 + mf * 16 + qk * 4 + j;
        float v = acc[mf][nf][j] + bb;
        if (DO_GELU) v = 0.5f * v * (1.0f + erff(v * 0.70710678118654752f));
        C[(size_t)r * N + ccol] = f2bf(v);
      }
    }
  }
}

// ---------------- FEM: 3 blockwise instance-norm gates fused + residual ----------------
__device__ __forceinline__ void fem_block(unsigned short* col, int t,
                                          int h0, int nh, int w0, int nw)
{
  float s = 0.f, s2 = 0.f;
  for (int ih = 0; ih < nh; ih++)
    for (int iw = 0; iw < nw; iw++) {
      const float v = bf2f(col[((h0 + ih) * 14 + w0 + iw) * 128 + t]);
      s += v; s2 += v * v;
    }
  const float inv = 1.0f / (float)(nh * nw);
  const float m = s * inv;
  const float var = s2 * inv - m * m;
  const float r = rsqrtf(var + 1e-5f);
  for (int ih = 0; ih < nh; ih++)
    for (int iw = 0; iw < nw; iw++) {
      const int idx = ((h0 + ih) * 14 + w0 + iw) * 128 + t;
      const float v = bf2f(col[idx]);
      const float a = 1.0f / (1.0f + __expf(-(v - m) * r));
      col[idx] = f2bf(0.5f * v * (1.0f + a));
    }
}

__global__ __launch_bounds__(128)
void fem_kernel(const unsigned short* __restrict__ z, const float* __restrict__ x,
                float* __restrict__ out)
{
  __shared__ unsigned short buf[CN * 128];   // 50,176 B; thread-private columns
  const int t = threadIdx.x;
  const int b = blockIdx.x >> 3;
  const int cc = blockIdx.x & 7;
  const int c = cc * 128 + t;
  const size_t base = (size_t)b * CN * CC + c;
  #pragma unroll 4
  for (int n = 0; n < CN; n++) buf[n * 128 + t] = z[base + (size_t)n * CC];
  const int st3[5] = {0, 3, 6, 9, 12};
  const int ln3[5] = {3, 3, 3, 3, 2};
  for (int i = 0; i < 5; i++)
    for (int j = 0; j < 5; j++)
      fem_block(buf, t, st3[i], ln3[i], st3[j], ln3[j]);
  for (int i = 0; i < 2; i++)
    for (int j = 0; j < 2; j++)
      fem_block(buf, t, i * 7, 7, j * 7, 7);
  fem_block(buf, t, 0, 14, 0, 14);
  #pragma unroll 4
  for (int n = 0; n < CN; n++)
    out[base + (size_t)n * CC] = x[base + (size_t)n * CC] + bf2f(buf[n * 128 + t]);
}

// ---------------- launch ----------------
extern "C" void kernel_launch(void* const* d_in, const int* in_sizes, int n_in,
                              void* d_out, int out_size, void* d_ws, size_t ws_size,
                              hipStream_t stream) {
  const float* x     = (const float*)d_in[0];
  const float* ln1_g = (const float*)d_in[1];
  const float* ln1_b = (const float*)d_in[2];
  const float* cw    = (const float*)d_in[3];
  const float* ln2_g = (const float*)d_in[4];
  const float* ln2_b = (const float*)d_in[5];
  const float* fc1_w = (const float*)d_in[6];
  const float* fc1_b = (const float*)d_in[7];
  const float* fc2_w = (const float*)d_in[8];
  const float* fc2_b = (const float*)d_in[9];
  float* out = (float*)d_out;
  char* ws = (char*)d_ws;

  // arena (peak ~149 MB)
  const size_t SZ = (size_t)CB * CHH * CKW * CC * 4;         // 29,360,128 B (packed uint)
  unsigned* Az = (unsigned*)(ws);
  unsigned* Bz = (unsigned*)(ws + SZ);
  unsigned short* A1   = (unsigned short*)(ws);              // Az dead after fft_h
  unsigned short* W1T  = (unsigned short*)(ws + SZ);         // Bz dead after fftinv_ln
  unsigned short* W2T  = (unsigned short*)(ws + SZ + (size_t)4096 * 1024 * 2);
  unsigned short* Hmid = (unsigned short*)(ws + SZ + (size_t)4096 * 1024 * 4);
  unsigned short* Z    = (unsigned short*)(ws);              // A1 dead after GEMM1

  // 1. fused LN1 + rfft along W (fp32 LN, packed bf16 complex out)
  ln_fftw<<<CB * CHH, 256, 0, stream>>>(x, ln1_g, ln1_b, Az);
  // 2. fft along H + filter + ifft along H (2 ch/thread)
  fft_h_filt<<<CB * CKW * 2, 256, 0, stream>>>(Az, cw, Bz);
  // 3. fused irfft along W + LN2 -> bf16 A1
  fftinv_ln<<<CB * CHH, 256, 0, stream>>>(Bz, ln2_g, ln2_b, A1);
  // 4. weight prep
  transpose_f32_bf16<<<dim3(4096 / 32, 1024 / 32), 256, 0, stream>>>(fc1_w, W1T, 1024, 4096);
  transpose_f32_bf16<<<dim3(1024 / 32, 4096 / 32), 256, 0, stream>>>(fc2_w, W2T, 4096, 1024);
  // 5. GEMM1 + bias + exact GELU -> Hmid bf16 (128x256 tiles, grid 16x98 = 1568)
  gemm128x256<1><<<dim3(1568), 256, 0, stream>>>(A1, W1T, fc1_b, Hmid, CROWS, 4096, 1024);
  // 6. GEMM2 + bias -> Z bf16 (grid 8x98 = 784)
  gemm128<0><<<dim3(784), 256, 0, stream>>>(Hmid, W2T, fc2_b, Z, CROWS, 1024, 4096);
  // 7. FEM x3 fused + residual -> out
  fem_kernel<<<CB * 8, 128, 0, stream>>>(Z, x, out);
}

// Round 13
// 460.947 us; speedup vs baseline: 1.0665x; 1.0665x over previous
//
#include <hip/hip_runtime.h>

// ---------------- problem constants ----------------
constexpr int CB = 64;          // batch
constexpr int CHH = 14, CWW = 14;
constexpr int CN = 196;         // CHH*CWW
constexpr int CC = 1024;        // channels
constexpr int CROWS = CB * CN;  // 12544
constexpr int CKW = 8;          // rfft bins along W

// twiddles: cos/sin(2*pi*m/14), m=0..13
constexpr float C14[14] = {
  1.0f, 0.9009688679024191f, 0.6234898018587336f, 0.2225209339563144f,
  -0.2225209339563144f, -0.6234898018587336f, -0.9009688679024191f, -1.0f,
  -0.9009688679024191f, -0.6234898018587336f, -0.2225209339563144f,
  0.2225209339563144f, 0.6234898018587336f, 0.9009688679024191f };
constexpr float S14[14] = {
  0.0f, 0.4338837391175581f, 0.7818314824680298f, 0.9749279121818236f,
  0.9749279121818236f, 0.7818314824680298f, 0.4338837391175581f, 0.0f,
  -0.4338837391175581f, -0.7818314824680298f, -0.9749279121818236f,
  -0.9749279121818236f, -0.7818314824680298f, -0.4338837391175581f };

typedef __attribute__((ext_vector_type(8))) short bf16x8;
typedef __attribute__((ext_vector_type(4))) float f32x4;

__device__ __forceinline__ unsigned short f2bf(float f) {
  unsigned u = __builtin_bit_cast(unsigned, f);
  u += 0x7FFFu + ((u >> 16) & 1u);   // RNE
  return (unsigned short)(u >> 16);
}
__device__ __forceinline__ float bf2f(unsigned short h) {
  return __builtin_bit_cast(float, (unsigned)h << 16);
}
__device__ __forceinline__ unsigned pack2(float re, float im) {
  return (unsigned)f2bf(re) | ((unsigned)f2bf(im) << 16);
}

__device__ __forceinline__ void gload_lds16(const void* g, void* l) {
  __builtin_amdgcn_global_load_lds(
      (const __attribute__((address_space(1))) void*)g,
      (__attribute__((address_space(3))) void*)l, 16, 0, 0);
}

#define WAITV(N)  asm volatile("s_waitcnt vmcnt(" #N ")" ::: "memory")

// ---------------- fused LN1 + rfft along W ----------------
__global__ __launch_bounds__(256)
void ln_fftw(const float* __restrict__ x, const float* __restrict__ gam,
             const float* __restrict__ bet, unsigned* __restrict__ Az)
{
  const int t = threadIdx.x;
  const int bid = blockIdx.x;             // b*14 + h
  const int h = bid % 14;
  const int b = bid / 14;
  const int c4 = t * 4;
  const size_t base = ((size_t)b * CN + (size_t)h * CWW) * CC + c4;
  float v[14][4];
  float sw[14], qw[14];
  #pragma unroll
  for (int w = 0; w < 14; w++) {
    const float4 u = *(const float4*)(x + base + (size_t)w * CC);
    v[w][0] = u.x; v[w][1] = u.y; v[w][2] = u.z; v[w][3] = u.w;
    sw[w] = u.x + u.y + u.z + u.w;
    qw[w] = u.x*u.x + u.y*u.y + u.z*u.z + u.w*u.w;
  }
  __shared__ float redS[14][4], redQ[14][4];
  const int wid = t >> 6, lane = t & 63;
  #pragma unroll
  for (int w = 0; w < 14; w++) {
    float a = sw[w], q = qw[w];
    #pragma unroll
    for (int o = 32; o > 0; o >>= 1) { a += __shfl_down(a, o); q += __shfl_down(q, o); }
    if (lane == 0) { redS[w][wid] = a; redQ[w][wid] = q; }
  }
  __syncthreads();
  const float4 g4 = *(const float4*)(gam + c4);
  const float4 b4 = *(const float4*)(bet + c4);
  const float gg[4] = {g4.x, g4.y, g4.z, g4.w};
  const float bb[4] = {b4.x, b4.y, b4.z, b4.w};
  #pragma unroll
  for (int w = 0; w < 14; w++) {
    const float a = redS[w][0] + redS[w][1] + redS[w][2] + redS[w][3];
    const float q = redQ[w][0] + redQ[w][1] + redQ[w][2] + redQ[w][3];
    const float mean = a * (1.0f / CC);
    const float var  = q * (1.0f / CC) - mean * mean;
    const float r = rsqrtf(var + 1e-5f);
    #pragma unroll
    for (int j = 0; j < 4; j++)
      v[w][j] = (v[w][j] - mean) * r * gg[j] + bb[j];
  }
  const size_t obase = (((size_t)b * CHH + h) * CKW) * CC + c4;
  #pragma unroll
  for (int kw = 0; kw < 8; kw++) {
    float sr[4] = {}, si[4] = {};
    #pragma unroll
    for (int w = 0; w < 14; w++) {
      const int m = (w * kw) % 14;
      #pragma unroll
      for (int j = 0; j < 4; j++) {
        sr[j] += v[w][j] * C14[m];
        si[j] -= v[w][j] * S14[m];
      }
    }
    uint4 o;
    o.x = pack2(sr[0], si[0]); o.y = pack2(sr[1], si[1]);
    o.z = pack2(sr[2], si[2]); o.w = pack2(sr[3], si[3]);
    *(uint4*)(Az + obase + (size_t)kw * CC) = o;
  }
}

// ---------------- fft along H + filter + ifft along H (packed, 2 ch/thread) ----------------
__global__ __launch_bounds__(256)
void fft_h_filt(const unsigned* __restrict__ Az, const float* __restrict__ cw,
                unsigned* __restrict__ Bz)
{
  const int t = threadIdx.x;
  const int bid = blockIdx.x;             // ((b*8)+kw)*2 + half
  const int half = bid & 1;
  const int tmp = bid >> 1;
  const int kw = tmp & 7;
  const int b = tmp >> 3;
  const int c2 = half * 512 + t * 2;
  const size_t base = (((size_t)b * CHH) * CKW + kw) * CC + c2;  // h stride = CKW*CC
  float ar[14][2], ai[14][2];
  #pragma unroll
  for (int h = 0; h < 14; h++) {
    const uint2 u = *(const uint2*)(Az + base + (size_t)h * (CKW * CC));
    ar[h][0] = bf2f((unsigned short)(u.x & 0xffff)); ai[h][0] = bf2f((unsigned short)(u.x >> 16));
    ar[h][1] = bf2f((unsigned short)(u.y & 0xffff)); ai[h][1] = bf2f((unsigned short)(u.y >> 16));
  }
  float fr[14][2], fi[14][2];
  #pragma unroll
  for (int kh = 0; kh < 14; kh++) {
    float yr[2] = {}, yi[2] = {};
    #pragma unroll
    for (int h = 0; h < 14; h++) {
      const int m = (h * kh) % 14;
      #pragma unroll
      for (int j = 0; j < 2; j++) {
        yr[j] += ar[h][j] * C14[m] + ai[h][j] * S14[m];
        yi[j] += ai[h][j] * C14[m] - ar[h][j] * S14[m];
      }
    }
    const float4 w4 = *(const float4*)(cw + ((size_t)(kh * CKW + kw) * CC + c2) * 2);
    fr[kh][0] = yr[0] * w4.x - yi[0] * w4.y; fi[kh][0] = yr[0] * w4.y + yi[0] * w4.x;
    fr[kh][1] = yr[1] * w4.z - yi[1] * w4.w; fi[kh][1] = yr[1] * w4.w + yi[1] * w4.z;
  }
  #pragma unroll
  for (int h = 0; h < 14; h++) {
    float sr[2] = {}, si[2] = {};
    #pragma unroll
    for (int kh = 0; kh < 14; kh++) {
      const int m = (h * kh) % 14;
      #pragma unroll
      for (int j = 0; j < 2; j++) {
        sr[j] += fr[kh][j] * C14[m] - fi[kh][j] * S14[m];
        si[j] += fr[kh][j] * S14[m] + fi[kh][j] * C14[m];
      }
    }
    uint2 o;
    o.x = pack2(sr[0], si[0]); o.y = pack2(sr[1], si[1]);
    *(uint2*)(Bz + base + (size_t)h * (CKW * CC)) = o;
  }
}

// ---------------- fused irfft along W + LN2 -> bf16 A1 ----------------
__global__ __launch_bounds__(256)
void fftinv_ln(const unsigned* __restrict__ Bz, const float* __restrict__ gam,
               const float* __restrict__ bet, unsigned short* __restrict__ A1)
{
  const int t = threadIdx.x;
  const int bid = blockIdx.x;             // b*14 + h
  const int h = bid % 14;
  const int b = bid / 14;
  const int c4 = t * 4;
  const size_t ibase = (((size_t)b * CHH + h) * CKW) * CC + c4;
  float br[8][4], bi[8][4];
  #pragma unroll
  for (int k = 0; k < 8; k++) {
    const uint4 u = *(const uint4*)(Bz + ibase + (size_t)k * CC);
    br[k][0] = bf2f((unsigned short)(u.x & 0xffff)); bi[k][0] = bf2f((unsigned short)(u.x >> 16));
    br[k][1] = bf2f((unsigned short)(u.y & 0xffff)); bi[k][1] = bf2f((unsigned short)(u.y >> 16));
    br[k][2] = bf2f((unsigned short)(u.z & 0xffff)); bi[k][2] = bf2f((unsigned short)(u.z >> 16));
    br[k][3] = bf2f((unsigned short)(u.w & 0xffff)); bi[k][3] = bf2f((unsigned short)(u.w >> 16));
  }
  float y[14][4];
  float sw[14], qw[14];
  #pragma unroll
  for (int w = 0; w < 14; w++) {
    float s[4];
    #pragma unroll
    for (int j = 0; j < 4; j++)
      s[j] = br[0][j] + ((w & 1) ? -br[7][j] : br[7][j]);
    #pragma unroll
    for (int k = 1; k < 7; k++) {
      const int m = (w * k) % 14;
      #pragma unroll
      for (int j = 0; j < 4; j++)
        s[j] += 2.0f * (br[k][j] * C14[m] - bi[k][j] * S14[m]);
    }
    float a = 0.f, q = 0.f;
    #pragma unroll
    for (int j = 0; j < 4; j++) {
      y[w][j] = s[j] * (1.0f / 196.0f);
      a += y[w][j];
      q += y[w][j] * y[w][j];
    }
    sw[w] = a; qw[w] = q;
  }
  __shared__ float redS[14][4], redQ[14][4];
  const int wid = t >> 6, lane = t & 63;
  #pragma unroll
  for (int w = 0; w < 14; w++) {
    float a = sw[w], q = qw[w];
    #pragma unroll
    for (int o = 32; o > 0; o >>= 1) { a += __shfl_down(a, o); q += __shfl_down(q, o); }
    if (lane == 0) { redS[w][wid] = a; redQ[w][wid] = q; }
  }
  __syncthreads();
  const float4 g4 = *(const float4*)(gam + c4);
  const float4 b4 = *(const float4*)(bet + c4);
  const float gg[4] = {g4.x, g4.y, g4.z, g4.w};
  const float bb[4] = {b4.x, b4.y, b4.z, b4.w};
  #pragma unroll
  for (int w = 0; w < 14; w++) {
    const float a = redS[w][0] + redS[w][1] + redS[w][2] + redS[w][3];
    const float q = redQ[w][0] + redQ[w][1] + redQ[w][2] + redQ[w][3];
    const float mean = a * (1.0f / CC);
    const float var  = q * (1.0f / CC) - mean * mean;
    const float r = rsqrtf(var + 1e-5f);
    ushort4 o;
    o.x = f2bf((y[w][0] - mean) * r * gg[0] + bb[0]);
    o.y = f2bf((y[w][1] - mean) * r * gg[1] + bb[1]);
    o.z = f2bf((y[w][2] - mean) * r * gg[2] + bb[2]);
    o.w = f2bf((y[w][3] - mean) * r * gg[3] + bb[3]);
    *(ushort4*)(A1 + ((size_t)b * CN + (size_t)h * CWW + w) * CC + c4) = o;
  }
}

// ---------------- fused weight transposes: both fc1_w and fc2_w in one launch ----------------
// blocks 0..4095:  fc1_w [1024,4096] -> W1T [4096,1024]  (x-blocks 128, y-blocks 32)
// blocks 4096..8191: fc2_w [4096,1024] -> W2T [1024,4096] (x-blocks 32, y-blocks 128)
__global__ __launch_bounds__(256)
void transpose_both(const float* __restrict__ w1, const float* __restrict__ w2,
                    unsigned short* __restrict__ W1T, unsigned short* __restrict__ W2T)
{
  __shared__ float tile[32][33];
  int id = blockIdx.x;
  const float* in; unsigned short* out; int R, Ccols, cb, rb;
  if (id < 4096) {
    in = w1; out = W1T; R = 1024; Ccols = 4096;
    cb = (id & 127) * 32; rb = (id >> 7) * 32;
  } else {
    id -= 4096;
    in = w2; out = W2T; R = 4096; Ccols = 1024;
    cb = (id & 31) * 32; rb = (id >> 5) * 32;
  }
  const int tx = threadIdx.x & 31;
  const int ty = threadIdx.x >> 5;     // 0..7
  #pragma unroll
  for (int i = 0; i < 32; i += 8)
    tile[ty + i][tx] = in[(size_t)(rb + ty + i) * Ccols + cb + tx];
  __syncthreads();
  #pragma unroll
  for (int i = 0; i < 32; i += 8)
    out[(size_t)(cb + ty + i) * R + rb + tx] = f2bf(tile[tx][ty + i]);
}

// ---------------- 128x128 bf16 GEMM, m97 structure, BK=64, 4 blocks/CU ----------------
// Proven R10/R11 config: 140us/dispatch, MfmaUtil 33%, VALUBusy 56%, conflicts 0.
// Structure optimum across 7 tested configs (R1-R12): cross-block TLP (4/CU)
// beats per-block LDS reuse (R9/R12 regressions) in single-buffered loops.
template<int DO_GELU>
__global__ __launch_bounds__(256, 4)
void gemm128(const unsigned short* __restrict__ A, const unsigned short* __restrict__ BT,
             const float* __restrict__ bias, unsigned short* __restrict__ C,
             int M, int N, int K)
{
  __shared__ __align__(16) char sA[16384];
  __shared__ __align__(16) char sB[16384];
  const int t = threadIdx.x;
  const int wid = t >> 6, lane = t & 63;
  const int wm = wid >> 1, wn = wid & 1;
  const int lrow = lane & 15, qk = lane >> 4;
  const int dq = qk << 4;

  // block mapping: groups of 8 brow-panels; within a group by-major then bx
  const int nbx = N >> 7, nby = M >> 7;
  const int per = nbx << 3;
  const int fullg = nby >> 3;
  int by, bx;
  if ((int)blockIdx.x < fullg * per) {
    const int g = blockIdx.x / per, r = blockIdx.x % per;
    by = (g << 3) + (r & 7); bx = r >> 3;
  } else {
    const int r = blockIdx.x - fullg * per;
    const int rem = nby - (fullg << 3);
    by = (fullg << 3) + r % rem; bx = r / rem;
  }
  const int brow = by << 7, bcol = bx << 7;

  // staging constants: 4 glds per matrix per K-step (region i = rows i*32..i*32+31)
  const int vr = t >> 3;                       // row within region (0..31)
  const int cl = ((t ^ (t >> 3)) & 7) << 3;    // inverse-swizzled elem col
  const int dstb = t * 16;                     // linear dest byte within region

  f32x4 acc[4][4] = {};

  for (int k0 = 0; k0 < K; k0 += 64) {
    __syncthreads();
    #pragma unroll
    for (int i = 0; i < 4; ++i) {
      gload_lds16(A  + (size_t)(brow + i * 32 + vr) * K + k0 + cl, sA + i * 4096 + dstb);
      gload_lds16(BT + (size_t)(bcol + i * 32 + vr) * K + k0 + cl, sB + i * 4096 + dstb);
    }
    WAITV(0);
    __syncthreads();
    #pragma unroll
    for (int ks = 0; ks < 2; ++ks) {
      bf16x8 af[4], bf[4];
      #pragma unroll
      for (int mf = 0; mf < 4; ++mf) {
        const int row = wm * 64 + mf * 16 + lrow;
        af[mf] = *(const bf16x8*)(sA + row * 128 + (((ks << 6) | dq) ^ ((row & 7) << 4)));
      }
      #pragma unroll
      for (int nf = 0; nf < 4; ++nf) {
        const int row = wn * 64 + nf * 16 + lrow;
        bf[nf] = *(const bf16x8*)(sB + row * 128 + (((ks << 6) | dq) ^ ((row & 7) << 4)));
      }
      #pragma unroll
      for (int mf = 0; mf < 4; ++mf)
        #pragma unroll
        for (int nf = 0; nf < 4; ++nf)
          acc[mf][nf] = __builtin_amdgcn_mfma_f32_16x16x32_bf16(af[mf], bf[nf],
                                                                acc[mf][nf], 0, 0, 0);
    }
  }

  // epilogue: bias (+GELU) + bf16 store
  #pragma unroll
  for (int mf = 0; mf < 4; ++mf) {
    #pragma unroll
    for (int nf = 0; nf < 4; ++nf) {
      const int ccol = bcol + wn * 64 + nf * 16 + lrow;
      const float bb = bias[ccol];
      #pragma unroll
      for (int j = 0; j < 4; ++j) {
        const int r = brow + wm * 64 + mf * 16 + qk * 4 + j;
        float v = acc[mf][nf][j] + bb;
        if (DO_GELU) v = 0.5f * v * (1.0f + erff(v * 0.70710678118654752f));
        C[(size_t)r * N + ccol] = f2bf(v);
      }
    }
  }
}

// ---------------- FEM: 3 blockwise instance-norm gates fused + residual ----------------
__device__ __forceinline__ void fem_block(unsigned short* col, int t,
                                          int h0, int nh, int w0, int nw)
{
  float s = 0.f, s2 = 0.f;
  for (int ih = 0; ih < nh; ih++)
    for (int iw = 0; iw < nw; iw++) {
      const float v = bf2f(col[((h0 + ih) * 14 + w0 + iw) * 128 + t]);
      s += v; s2 += v * v;
    }
  const float inv = 1.0f / (float)(nh * nw);
  const float m = s * inv;
  const float var = s2 * inv - m * m;
  const float r = rsqrtf(var + 1e-5f);
  for (int ih = 0; ih < nh; ih++)
    for (int iw = 0; iw < nw; iw++) {
      const int idx = ((h0 + ih) * 14 + w0 + iw) * 128 + t;
      const float v = bf2f(col[idx]);
      const float a = 1.0f / (1.0f + __expf(-(v - m) * r));
      col[idx] = f2bf(0.5f * v * (1.0f + a));
    }
}

__global__ __launch_bounds__(128)
void fem_kernel(const unsigned short* __restrict__ z, const float* __restrict__ x,
                float* __restrict__ out)
{
  __shared__ unsigned short buf[CN * 128];   // 50,176 B; thread-private columns
  const int t = threadIdx.x;
  const int b = blockIdx.x >> 3;
  const int cc = blockIdx.x & 7;
  const int c = cc * 128 + t;
  const size_t base = (size_t)b * CN * CC + c;
  #pragma unroll 4
  for (int n = 0; n < CN; n++) buf[n * 128 + t] = z[base + (size_t)n * CC];
  const int st3[5] = {0, 3, 6, 9, 12};
  const int ln3[5] = {3, 3, 3, 3, 2};
  for (int i = 0; i < 5; i++)
    for (int j = 0; j < 5; j++)
      fem_block(buf, t, st3[i], ln3[i], st3[j], ln3[j]);
  for (int i = 0; i < 2; i++)
    for (int j = 0; j < 2; j++)
      fem_block(buf, t, i * 7, 7, j * 7, 7);
  fem_block(buf, t, 0, 14, 0, 14);
  #pragma unroll 4
  for (int n = 0; n < CN; n++)
    out[base + (size_t)n * CC] = x[base + (size_t)n * CC] + bf2f(buf[n * 128 + t]);
}

// ---------------- launch ----------------
extern "C" void kernel_launch(void* const* d_in, const int* in_sizes, int n_in,
                              void* d_out, int out_size, void* d_ws, size_t ws_size,
                              hipStream_t stream) {
  const float* x     = (const float*)d_in[0];
  const float* ln1_g = (const float*)d_in[1];
  const float* ln1_b = (const float*)d_in[2];
  const float* cw    = (const float*)d_in[3];
  const float* ln2_g = (const float*)d_in[4];
  const float* ln2_b = (const float*)d_in[5];
  const float* fc1_w = (const float*)d_in[6];
  const float* fc1_b = (const float*)d_in[7];
  const float* fc2_w = (const float*)d_in[8];
  const float* fc2_b = (const float*)d_in[9];
  float* out = (float*)d_out;
  char* ws = (char*)d_ws;

  // arena (peak ~149 MB)
  const size_t SZ = (size_t)CB * CHH * CKW * CC * 4;         // 29,360,128 B (packed uint)
  unsigned* Az = (unsigned*)(ws);
  unsigned* Bz = (unsigned*)(ws + SZ);
  unsigned short* A1   = (unsigned short*)(ws);              // Az dead after fft_h
  unsigned short* W1T  = (unsigned short*)(ws + SZ);         // Bz dead after fftinv_ln
  unsigned short* W2T  = (unsigned short*)(ws + SZ + (size_t)4096 * 1024 * 2);
  unsigned short* Hmid = (unsigned short*)(ws + SZ + (size_t)4096 * 1024 * 4);
  unsigned short* Z    = (unsigned short*)(ws);              // A1 dead after GEMM1

  // 1. fused LN1 + rfft along W (fp32 LN, packed bf16 complex out)
  ln_fftw<<<CB * CHH, 256, 0, stream>>>(x, ln1_g, ln1_b, Az);
  // 2. fft along H + filter + ifft along H (2 ch/thread)
  fft_h_filt<<<CB * CKW * 2, 256, 0, stream>>>(Az, cw, Bz);
  // 3. fused irfft along W + LN2 -> bf16 A1
  fftinv_ln<<<CB * CHH, 256, 0, stream>>>(Bz, ln2_g, ln2_b, A1);
  // 4. both weight transposes in one launch
  transpose_both<<<dim3(8192), 256, 0, stream>>>(fc1_w, fc2_w, W1T, W2T);
  // 5. GEMM1 + bias + exact GELU -> Hmid bf16 (grid 32x98 = 3136)
  gemm128<1><<<dim3(3136), 256, 0, stream>>>(A1, W1T, fc1_b, Hmid, CROWS, 4096, 1024);
  // 6. GEMM2 + bias -> Z bf16 (grid 8x98 = 784)
  gemm128<0><<<dim3(784), 256, 0, stream>>>(Hmid, W2T, fc2_b, Z, CROWS, 1024, 4096);
  // 7. FEM x3 fused + residual -> out
  fem_kernel<<<CB * 8, 128, 0, stream>>>(Z, x, out);
}

// Round 14
// 455.705 us; speedup vs baseline: 1.0788x; 1.0115x over previous
//
#include <hip/hip_runtime.h>

// ---------------- problem constants ----------------
constexpr int CB = 64;          // batch
constexpr int CHH = 14, CWW = 14;
constexpr int CN = 196;         // CHH*CWW
constexpr int CC = 1024;        // channels
constexpr int CROWS = CB * CN;  // 12544
constexpr int CKW = 8;          // rfft bins along W

// twiddles: cos/sin(2*pi*m/14), m=0..13
constexpr float C14[14] = {
  1.0f, 0.9009688679024191f, 0.6234898018587336f, 0.2225209339563144f,
  -0.2225209339563144f, -0.6234898018587336f, -0.9009688679024191f, -1.0f,
  -0.9009688679024191f, -0.6234898018587336f, -0.2225209339563144f,
  0.2225209339563144f, 0.6234898018587336f, 0.9009688679024191f };
constexpr float S14[14] = {
  0.0f, 0.4338837391175581f, 0.7818314824680298f, 0.9749279121818236f,
  0.9749279121818236f, 0.7818314824680298f, 0.4338837391175581f, 0.0f,
  -0.4338837391175581f, -0.7818314824680298f, -0.9749279121818236f,
  -0.9749279121818236f, -0.7818314824680298f, -0.4338837391175581f };

typedef __attribute__((ext_vector_type(8))) short bf16x8;
typedef __attribute__((ext_vector_type(4))) float f32x4;

__device__ __forceinline__ unsigned short f2bf(float f) {
  unsigned u = __builtin_bit_cast(unsigned, f);
  u += 0x7FFFu + ((u >> 16) & 1u);   // RNE
  return (unsigned short)(u >> 16);
}
__device__ __forceinline__ float bf2f(unsigned short h) {
  return __builtin_bit_cast(float, (unsigned)h << 16);
}
__device__ __forceinline__ unsigned pack2(float re, float im) {
  return (unsigned)f2bf(re) | ((unsigned)f2bf(im) << 16);
}

__device__ __forceinline__ void gload_lds16(const void* g, void* l) {
  __builtin_amdgcn_global_load_lds(
      (const __attribute__((address_space(1))) void*)g,
      (__attribute__((address_space(3))) void*)l, 16, 0, 0);
}

#define WAITV(N)  asm volatile("s_waitcnt vmcnt(" #N ")" ::: "memory")

// ---------------- fused LN1 + rfft along W ----------------
__global__ __launch_bounds__(256)
void ln_fftw(const float* __restrict__ x, const float* __restrict__ gam,
             const float* __restrict__ bet, unsigned* __restrict__ Az)
{
  const int t = threadIdx.x;
  const int bid = blockIdx.x;             // b*14 + h
  const int h = bid % 14;
  const int b = bid / 14;
  const int c4 = t * 4;
  const size_t base = ((size_t)b * CN + (size_t)h * CWW) * CC + c4;
  float v[14][4];
  float sw[14], qw[14];
  #pragma unroll
  for (int w = 0; w < 14; w++) {
    const float4 u = *(const float4*)(x + base + (size_t)w * CC);
    v[w][0] = u.x; v[w][1] = u.y; v[w][2] = u.z; v[w][3] = u.w;
    sw[w] = u.x + u.y + u.z + u.w;
    qw[w] = u.x*u.x + u.y*u.y + u.z*u.z + u.w*u.w;
  }
  __shared__ float redS[14][4], redQ[14][4];
  const int wid = t >> 6, lane = t & 63;
  #pragma unroll
  for (int w = 0; w < 14; w++) {
    float a = sw[w], q = qw[w];
    #pragma unroll
    for (int o = 32; o > 0; o >>= 1) { a += __shfl_down(a, o); q += __shfl_down(q, o); }
    if (lane == 0) { redS[w][wid] = a; redQ[w][wid] = q; }
  }
  __syncthreads();
  const float4 g4 = *(const float4*)(gam + c4);
  const float4 b4 = *(const float4*)(bet + c4);
  const float gg[4] = {g4.x, g4.y, g4.z, g4.w};
  const float bb[4] = {b4.x, b4.y, b4.z, b4.w};
  #pragma unroll
  for (int w = 0; w < 14; w++) {
    const float a = redS[w][0] + redS[w][1] + redS[w][2] + redS[w][3];
    const float q = redQ[w][0] + redQ[w][1] + redQ[w][2] + redQ[w][3];
    const float mean = a * (1.0f / CC);
    const float var  = q * (1.0f / CC) - mean * mean;
    const float r = rsqrtf(var + 1e-5f);
    #pragma unroll
    for (int j = 0; j < 4; j++)
      v[w][j] = (v[w][j] - mean) * r * gg[j] + bb[j];
  }
  const size_t obase = (((size_t)b * CHH + h) * CKW) * CC + c4;
  #pragma unroll
  for (int kw = 0; kw < 8; kw++) {
    float sr[4] = {}, si[4] = {};
    #pragma unroll
    for (int w = 0; w < 14; w++) {
      const int m = (w * kw) % 14;
      #pragma unroll
      for (int j = 0; j < 4; j++) {
        sr[j] += v[w][j] * C14[m];
        si[j] -= v[w][j] * S14[m];
      }
    }
    uint4 o;
    o.x = pack2(sr[0], si[0]); o.y = pack2(sr[1], si[1]);
    o.z = pack2(sr[2], si[2]); o.w = pack2(sr[3], si[3]);
    *(uint4*)(Az + obase + (size_t)kw * CC) = o;
  }
}

// ---------------- fft along H + filter + ifft along H (packed, 2 ch/thread) ----------------
__global__ __launch_bounds__(256)
void fft_h_filt(const unsigned* __restrict__ Az, const float* __restrict__ cw,
                unsigned* __restrict__ Bz)
{
  const int t = threadIdx.x;
  const int bid = blockIdx.x;             // ((b*8)+kw)*2 + half
  const int half = bid & 1;
  const int tmp = bid >> 1;
  const int kw = tmp & 7;
  const int b = tmp >> 3;
  const int c2 = half * 512 + t * 2;
  const size_t base = (((size_t)b * CHH) * CKW + kw) * CC + c2;  // h stride = CKW*CC
  float ar[14][2], ai[14][2];
  #pragma unroll
  for (int h = 0; h < 14; h++) {
    const uint2 u = *(const uint2*)(Az + base + (size_t)h * (CKW * CC));
    ar[h][0] = bf2f((unsigned short)(u.x & 0xffff)); ai[h][0] = bf2f((unsigned short)(u.x >> 16));
    ar[h][1] = bf2f((unsigned short)(u.y & 0xffff)); ai[h][1] = bf2f((unsigned short)(u.y >> 16));
  }
  float fr[14][2], fi[14][2];
  #pragma unroll
  for (int kh = 0; kh < 14; kh++) {
    float yr[2] = {}, yi[2] = {};
    #pragma unroll
    for (int h = 0; h < 14; h++) {
      const int m = (h * kh) % 14;
      #pragma unroll
      for (int j = 0; j < 2; j++) {
        yr[j] += ar[h][j] * C14[m] + ai[h][j] * S14[m];
        yi[j] += ai[h][j] * C14[m] - ar[h][j] * S14[m];
      }
    }
    const float4 w4 = *(const float4*)(cw + ((size_t)(kh * CKW + kw) * CC + c2) * 2);
    fr[kh][0] = yr[0] * w4.x - yi[0] * w4.y; fi[kh][0] = yr[0] * w4.y + yi[0] * w4.x;
    fr[kh][1] = yr[1] * w4.z - yi[1] * w4.w; fi[kh][1] = yr[1] * w4.w + yi[1] * w4.z;
  }
  #pragma unroll
  for (int h = 0; h < 14; h++) {
    float sr[2] = {}, si[2] = {};
    #pragma unroll
    for (int kh = 0; kh < 14; kh++) {
      const int m = (h * kh) % 14;
      #pragma unroll
      for (int j = 0; j < 2; j++) {
        sr[j] += fr[kh][j] * C14[m] - fi[kh][j] * S14[m];
        si[j] += fr[kh][j] * S14[m] + fi[kh][j] * C14[m];
      }
    }
    uint2 o;
    o.x = pack2(sr[0], si[0]); o.y = pack2(sr[1], si[1]);
    *(uint2*)(Bz + base + (size_t)h * (CKW * CC)) = o;
  }
}

// ---------------- fused irfft along W + LN2 -> bf16 A1 ----------------
__global__ __launch_bounds__(256)
void fftinv_ln(const unsigned* __restrict__ Bz, const float* __restrict__ gam,
               const float* __restrict__ bet, unsigned short* __restrict__ A1)
{
  const int t = threadIdx.x;
  const int bid = blockIdx.x;             // b*14 + h
  const int h = bid % 14;
  const int b = bid / 14;
  const int c4 = t * 4;
  const size_t ibase = (((size_t)b * CHH + h) * CKW) * CC + c4;
  float br[8][4], bi[8][4];
  #pragma unroll
  for (int k = 0; k < 8; k++) {
    const uint4 u = *(const uint4*)(Bz + ibase + (size_t)k * CC);
    br[k][0] = bf2f((unsigned short)(u.x & 0xffff)); bi[k][0] = bf2f((unsigned short)(u.x >> 16));
    br[k][1] = bf2f((unsigned short)(u.y & 0xffff)); bi[k][1] = bf2f((unsigned short)(u.y >> 16));
    br[k][2] = bf2f((unsigned short)(u.z & 0xffff)); bi[k][2] = bf2f((unsigned short)(u.z >> 16));
    br[k][3] = bf2f((unsigned short)(u.w & 0xffff)); bi[k][3] = bf2f((unsigned short)(u.w >> 16));
  }
  float y[14][4];
  float sw[14], qw[14];
  #pragma unroll
  for (int w = 0; w < 14; w++) {
    float s[4];
    #pragma unroll
    for (int j = 0; j < 4; j++)
      s[j] = br[0][j] + ((w & 1) ? -br[7][j] : br[7][j]);
    #pragma unroll
    for (int k = 1; k < 7; k++) {
      const int m = (w * k) % 14;
      #pragma unroll
      for (int j = 0; j < 4; j++)
        s[j] += 2.0f * (br[k][j] * C14[m] - bi[k][j] * S14[m]);
    }
    float a = 0.f, q = 0.f;
    #pragma unroll
    for (int j = 0; j < 4; j++) {
      y[w][j] = s[j] * (1.0f / 196.0f);
      a += y[w][j];
      q += y[w][j] * y[w][j];
    }
    sw[w] = a; qw[w] = q;
  }
  __shared__ float redS[14][4], redQ[14][4];
  const int wid = t >> 6, lane = t & 63;
  #pragma unroll
  for (int w = 0; w < 14; w++) {
    float a = sw[w], q = qw[w];
    #pragma unroll
    for (int o = 32; o > 0; o >>= 1) { a += __shfl_down(a, o); q += __shfl_down(q, o); }
    if (lane == 0) { redS[w][wid] = a; redQ[w][wid] = q; }
  }
  __syncthreads();
  const float4 g4 = *(const float4*)(gam + c4);
  const float4 b4 = *(const float4*)(bet + c4);
  const float gg[4] = {g4.x, g4.y, g4.z, g4.w};
  const float bb[4] = {b4.x, b4.y, b4.z, b4.w};
  #pragma unroll
  for (int w = 0; w < 14; w++) {
    const float a = redS[w][0] + redS[w][1] + redS[w][2] + redS[w][3];
    const float q = redQ[w][0] + redQ[w][1] + redQ[w][2] + redQ[w][3];
    const float mean = a * (1.0f / CC);
    const float var  = q * (1.0f / CC) - mean * mean;
    const float r = rsqrtf(var + 1e-5f);
    ushort4 o;
    o.x = f2bf((y[w][0] - mean) * r * gg[0] + bb[0]);
    o.y = f2bf((y[w][1] - mean) * r * gg[1] + bb[1]);
    o.z = f2bf((y[w][2] - mean) * r * gg[2] + bb[2]);
    o.w = f2bf((y[w][3] - mean) * r * gg[3] + bb[3]);
    *(ushort4*)(A1 + ((size_t)b * CN + (size_t)h * CWW + w) * CC + c4) = o;
  }
}

// ---------------- fused weight transposes: both fc1_w and fc2_w in one launch ----------------
__global__ __launch_bounds__(256)
void transpose_both(const float* __restrict__ w1, const float* __restrict__ w2,
                    unsigned short* __restrict__ W1T, unsigned short* __restrict__ W2T)
{
  __shared__ float tile[32][33];
  int id = blockIdx.x;
  const float* in; unsigned short* out; int R, Ccols, cb, rb;
  if (id < 4096) {
    in = w1; out = W1T; R = 1024; Ccols = 4096;
    cb = (id & 127) * 32; rb = (id >> 7) * 32;
  } else {
    id -= 4096;
    in = w2; out = W2T; R = 4096; Ccols = 1024;
    cb = (id & 31) * 32; rb = (id >> 5) * 32;
  }
  const int tx = threadIdx.x & 31;
  const int ty = threadIdx.x >> 5;     // 0..7
  #pragma unroll
  for (int i = 0; i < 32; i += 8)
    tile[ty + i][tx] = in[(size_t)(rb + ty + i) * Ccols + cb + tx];
  __syncthreads();
  #pragma unroll
  for (int i = 0; i < 32; i += 8)
    out[(size_t)(cb + ty + i) * R + rb + tx] = f2bf(tile[tx][ty + i]);
}

// ---------------- 128x128 bf16 GEMM, m97 structure + XCD-aware block swizzle ----------------
// R10 config (140us, MfmaUtil 33%, conflicts 0) + T1: m204 bijective XCD swizzle
// prepended to the group-of-8 ordering. Without it, consecutive logical blocks
// round-robin across the 8 XCDs' private L2s, scattering each locality group
// over 8 caches -> measured 2.3x HBM over-fetch (280MB vs ~120MB ideal).
// With it, each XCD owns a contiguous run of groups: A-group (2MB) stays hot
// in its L2 and each B-panel streams once per XCD.
template<int DO_GELU>
__global__ __launch_bounds__(256, 4)
void gemm128(const unsigned short* __restrict__ A, const unsigned short* __restrict__ BT,
             const float* __restrict__ bias, unsigned short* __restrict__ C,
             int M, int N, int K)
{
  __shared__ __align__(16) char sA[16384];
  __shared__ __align__(16) char sB[16384];
  const int t = threadIdx.x;
  const int wid = t >> 6, lane = t & 63;
  const int wm = wid >> 1, wn = wid & 1;
  const int lrow = lane & 15, qk = lane >> 4;
  const int dq = qk << 4;

  // T1: XCD swizzle (both grids are %8==0: 3136, 784) -> contiguous logical
  // range per XCD; then group-of-8 brow-panels, by-major then bx within group.
  const int nbx = N >> 7, nby = M >> 7;
  const int nwg = nbx * nby;
  const int orig = blockIdx.x;
  int wg = orig;
  if ((nwg & 7) == 0) {
    const int q8 = nwg >> 3;
    wg = (orig & 7) * q8 + (orig >> 3);
  }
  const int per = nbx << 3;
  const int fullg = nby >> 3;
  int by, bx;
  if (wg < fullg * per) {
    const int g = wg / per, r = wg % per;
    by = (g << 3) + (r & 7); bx = r >> 3;
  } else {
    const int r = wg - fullg * per;
    const int rem = nby - (fullg << 3);
    by = (fullg << 3) + r % rem; bx = r / rem;
  }
  const int brow = by << 7, bcol = bx << 7;

  // staging constants: 4 glds per matrix per K-step (region i = rows i*32..i*32+31)
  const int vr = t >> 3;                       // row within region (0..31)
  const int cl = ((t ^ (t >> 3)) & 7) << 3;    // inverse-swizzled elem col
  const int dstb = t * 16;                     // linear dest byte within region

  f32x4 acc[4][4] = {};

  for (int k0 = 0; k0 < K; k0 += 64) {
    __syncthreads();
    #pragma unroll
    for (int i = 0; i < 4; ++i) {
      gload_lds16(A  + (size_t)(brow + i * 32 + vr) * K + k0 + cl, sA + i * 4096 + dstb);
      gload_lds16(BT + (size_t)(bcol + i * 32 + vr) * K + k0 + cl, sB + i * 4096 + dstb);
    }
    WAITV(0);
    __syncthreads();
    #pragma unroll
    for (int ks = 0; ks < 2; ++ks) {
      bf16x8 af[4], bf[4];
      #pragma unroll
      for (int mf = 0; mf < 4; ++mf) {
        const int row = wm * 64 + mf * 16 + lrow;
        af[mf] = *(const bf16x8*)(sA + row * 128 + (((ks << 6) | dq) ^ ((row & 7) << 4)));
      }
      #pragma unroll
      for (int nf = 0; nf < 4; ++nf) {
        const int row = wn * 64 + nf * 16 + lrow;
        bf[nf] = *(const bf16x8*)(sB + row * 128 + (((ks << 6) | dq) ^ ((row & 7) << 4)));
      }
      #pragma unroll
      for (int mf = 0; mf < 4; ++mf)
        #pragma unroll
        for (int nf = 0; nf < 4; ++nf)
          acc[mf][nf] = __builtin_amdgcn_mfma_f32_16x16x32_bf16(af[mf], bf[nf],
                                                                acc[mf][nf], 0, 0, 0);
    }
  }

  // epilogue: bias (+GELU) + bf16 store
  #pragma unroll
  for (int mf = 0; mf < 4; ++mf) {
    #pragma unroll
    for (int nf = 0; nf < 4; ++nf) {
      const int ccol = bcol + wn * 64 + nf * 16 + lrow;
      const float bb = bias[ccol];
      #pragma unroll
      for (int j = 0; j < 4; ++j) {
        const int r = brow + wm * 64 + mf * 16 + qk * 4 + j;
        float v = acc[mf][nf][j] + bb;
        if (DO_GELU) v = 0.5f * v * (1.0f + erff(v * 0.70710678118654752f));
        C[(size_t)r * N + ccol] = f2bf(v);
      }
    }
  }
}

// ---------------- FEM: 3 blockwise instance-norm gates fused + residual ----------------
__device__ __forceinline__ void fem_block(unsigned short* col, int t,
                                          int h0, int nh, int w0, int nw)
{
  float s = 0.f, s2 = 0.f;
  for (int ih = 0; ih < nh; ih++)
    for (int iw = 0; iw < nw; iw++) {
      const float v = bf2f(col[((h0 + ih) * 14 + w0 + iw) * 128 + t]);
      s += v; s2 += v * v;
    }
  const float inv = 1.0f / (float)(nh * nw);
  const float m = s * inv;
  const float var = s2 * inv - m * m;
  const float r = rsqrtf(var + 1e-5f);
  for (int ih = 0; ih < nh; ih++)
    for (int iw = 0; iw < nw; iw++) {
      const int idx = ((h0 + ih) * 14 + w0 + iw) * 128 + t;
      const float v = bf2f(col[idx]);
      const float a = 1.0f / (1.0f + __expf(-(v - m) * r));
      col[idx] = f2bf(0.5f * v * (1.0f + a));
    }
}

__global__ __launch_bounds__(128)
void fem_kernel(const unsigned short* __restrict__ z, const float* __restrict__ x,
                float* __restrict__ out)
{
  __shared__ unsigned short buf[CN * 128];   // 50,176 B; thread-private columns
  const int t = threadIdx.x;
  const int b = blockIdx.x >> 3;
  const int cc = blockIdx.x & 7;
  const int c = cc * 128 + t;
  const size_t base = (size_t)b * CN * CC + c;
  #pragma unroll 4
  for (int n = 0; n < CN; n++) buf[n * 128 + t] = z[base + (size_t)n * CC];
  const int st3[5] = {0, 3, 6, 9, 12};
  const int ln3[5] = {3, 3, 3, 3, 2};
  for (int i = 0; i < 5; i++)
    for (int j = 0; j < 5; j++)
      fem_block(buf, t, st3[i], ln3[i], st3[j], ln3[j]);
  for (int i = 0; i < 2; i++)
    for (int j = 0; j < 2; j++)
      fem_block(buf, t, i * 7, 7, j * 7, 7);
  fem_block(buf, t, 0, 14, 0, 14);
  #pragma unroll 4
  for (int n = 0; n < CN; n++)
    out[base + (size_t)n * CC] = x[base + (size_t)n * CC] + bf2f(buf[n * 128 + t]);
}

// ---------------- launch ----------------
extern "C" void kernel_launch(void* const* d_in, const int* in_sizes, int n_in,
                              void* d_out, int out_size, void* d_ws, size_t ws_size,
                              hipStream_t stream) {
  const float* x     = (const float*)d_in[0];
  const float* ln1_g = (const float*)d_in[1];
  const float* ln1_b = (const float*)d_in[2];
  const float* cw    = (const float*)d_in[3];
  const float* ln2_g = (const float*)d_in[4];
  const float* ln2_b = (const float*)d_in[5];
  const float* fc1_w = (const float*)d_in[6];
  const float* fc1_b = (const float*)d_in[7];
  const float* fc2_w = (const float*)d_in[8];
  const float* fc2_b = (const float*)d_in[9];
  float* out = (float*)d_out;
  char* ws = (char*)d_ws;

  // arena (peak ~149 MB)
  const size_t SZ = (size_t)CB * CHH * CKW * CC * 4;         // 29,360,128 B (packed uint)
  unsigned* Az = (unsigned*)(ws);
  unsigned* Bz = (unsigned*)(ws + SZ);
  unsigned short* A1   = (unsigned short*)(ws);              // Az dead after fft_h
  unsigned short* W1T  = (unsigned short*)(ws + SZ);         // Bz dead after fftinv_ln
  unsigned short* W2T  = (unsigned short*)(ws + SZ + (size_t)4096 * 1024 * 2);
  unsigned short* Hmid = (unsigned short*)(ws + SZ + (size_t)4096 * 1024 * 4);
  unsigned short* Z    = (unsigned short*)(ws);              // A1 dead after GEMM1

  // 1. fused LN1 + rfft along W (fp32 LN, packed bf16 complex out)
  ln_fftw<<<CB * CHH, 256, 0, stream>>>(x, ln1_g, ln1_b, Az);
  // 2. fft along H + filter + ifft along H (2 ch/thread)
  fft_h_filt<<<CB * CKW * 2, 256, 0, stream>>>(Az, cw, Bz);
  // 3. fused irfft along W + LN2 -> bf16 A1
  fftinv_ln<<<CB * CHH, 256, 0, stream>>>(Bz, ln2_g, ln2_b, A1);
  // 4. both weight transposes in one launch
  transpose_both<<<dim3(8192), 256, 0, stream>>>(fc1_w, fc2_w, W1T, W2T);
  // 5. GEMM1 + bias + exact GELU -> Hmid bf16 (grid 32x98 = 3136)
  gemm128<1><<<dim3(3136), 256, 0, stream>>>(A1, W1T, fc1_b, Hmid, CROWS, 4096, 1024);
  // 6. GEMM2 + bias -> Z bf16 (grid 8x98 = 784)
  gemm128<0><<<dim3(784), 256, 0, stream>>>(Hmid, W2T, fc2_b, Z, CROWS, 1024, 4096);
  // 7. FEM x3 fused + residual -> out
  fem_kernel<<<CB * 8, 128, 0, stream>>>(Z, x, out);
}